// Round 6
// baseline (523.549 us; speedup 1.0000x reference)
//
#include <hip/hip_runtime.h>

// SparseSpikingConv2D — Round 12: single-product fp16 conv; registers fit.
// R11 post-mortem: FETCH 55->79, WRITE 147->178 (+55 MB scratch round-trip),
// VGPR capped 128 vs ~210 live (wH+wL=144 alone) -> compiler rematerialized
// weight loads in-loop: weight-stationarity silently broken, per-row wall 52K
// cyc vs ~14K pipe work. The hi/lo WEIGHT split is the register breaker.
// Numerics: mthr error scales by (1-beta)/norm ~= 0.139. Dropping wl AND xl
// products: sigma(mthr) ~= 2.6e-5; EPSB back to 2e-4 = 7.7 sigma (R0-R4
// proven band) -> single fp16 x fp16 product. fixB back to ~13K flags (+48us,
// measured R4<->R5) but convM: MFMA /3, LDS reads /2 (no bl), ring /2
// (33.8 KB -> 4 blocks/CU), weights 72 VGPR. Budget ~122 <= 128 ->
// __launch_bounds__(256,4), 16 waves/CU, grid 1024 (4-row stripes).
// Floors: HBM ~40us (binding), LDS ~25, MFMA ~10.

typedef _Float16 half8 __attribute__((ext_vector_type(8)));
typedef float f32x4 __attribute__((ext_vector_type(4)));

constexpr int CIc = 64, COc = 128, HHc = 64, WWc = 64, NBc = 32;
constexpr float EPSB = 2e-4f;        // borderline band on mthr (7.7 sigma)
constexpr unsigned CAPc = 1u << 18;  // fixup list capacity (~13K expected)

// workspace layout (bytes)
constexpr size_t O_CNT   = 0;                    // 1 uint (padded 16)
constexpr size_t O_NORMD = 16;                   // 128 double
constexpr size_t O_RNORM = O_NORMD + 1024;       // 128 float
constexpr size_t O_WDT   = O_RNORM + 512;        // [co][t][ci] double = 589824 B
constexpr size_t O_WHI   = O_WDT + 589824;       // [t][co][ci] fp16 = 147456 B
constexpr size_t O_LIST  = O_WHI + 147456;       // CAPc uint
constexpr size_t WS_NEED = O_LIST + (size_t)CAPc * 4;   // ~1.8 MB

// Fused prep: blocks 0..127 -> norm (co=bx, 64-lane fp64 butterfly);
// blocks 128..415 -> wdT (fp64, for fixB) + whi (fp16, for convM).
__global__ void prep_kernel(const float* __restrict__ w, double* __restrict__ normd,
                            float* __restrict__ rnormf, double* __restrict__ wdT,
                            _Float16* __restrict__ whi, unsigned* __restrict__ counter) {
    const int bx = blockIdx.x;
    if (bx < 128) {
        const int co = bx, lane = threadIdx.x & 63;
        if (threadIdx.x >= 64) return;
        double s = 0.0;
        #pragma unroll
        for (int k = 0; k < 9; ++k) {
            const double v = (double)w[(k * 64 + lane) * COc + co];
            s = fma(v, v, s);
        }
        #pragma unroll
        for (int off = 32; off; off >>= 1) s += __shfl_xor(s, off);
        if (lane == 0) {
            s += 1e-8;
            normd[co]  = s;
            rnormf[co] = (float)(1.0 / s);
            if (co == 0) counter[0] = 0u;
        }
    } else {
        const int i = (bx - 128) * 256 + threadIdx.x;  // over 73728
        if (i >= 9 * CIc * COc) return;
        const int ci = i & 63, t = (i >> 6) % 9, co = i / (9 * 64);
        const float v = w[(t * CIc + ci) * COc + co];
        wdT[i] = (double)v;                            // wdT[co][t][ci]
        if (whi) {
            const int i2 = (t * COc + co) * CIc + ci;  // [t][co][ci]
            whi[i2] = (_Float16)v;
        }
    }
}

// ---- Pass A (MFMA, single-product fp16): 64co x 64px x 4 streamed rows ----
// Block = 256 thr = 4 waves; wave wv owns couts [co0, co0+16), co0 =
// cohalf*64 + wv*16; weights hi-only in 72 VGPRs (wH[9][2]).
// 4-slot LDS row ring (hi stream only, 8448 B/slot, 33792 B total ->
// 4 blocks/CU = 16 waves). Grid (16,2,32) = 1024 blocks (4-row stripes).
// Per row j: writeRow(y+2) -> MFMA (72 ds_read + 72 MFMA) -> epilogue
// (mem loads inline) -> issueRow(y+3) -> lgkmcnt(0); raw s_barrier
// (vmem stays in flight). Swizzle byte^=(px1&7)<<4 on write AND read.
// D: row=co=(lane>>4)*4+r, col=px=lane&15 (m89 layout).
__global__ __launch_bounds__(256, 4) void convM(
    const float* __restrict__ x,       // [32,64,64,64]
    const float* __restrict__ mem,     // [32,128,64,64]
    const _Float16* __restrict__ whi,  // [9,128,64]
    const float* __restrict__ beta_p,
    const float* __restrict__ bias,
    const float* __restrict__ rnormf,
    float* __restrict__ out_spk, float* __restrict__ out_mem,
    unsigned* __restrict__ counter, unsigned* __restrict__ list)
{
    // 4 slots x 8448 B (66 px1 x 64 ci fp16, swizzled) = 33792 B.
    __shared__ half8 xs[2112];
    char* xsb = (char*)(&xs[0]);

    const int tid = threadIdx.x;
    const int y0 = blockIdx.x * 4;
    const int cohalf = blockIdx.y;
    const int n = blockIdx.z;

    const int lane   = tid & 63;
    const int wv     = tid >> 6;
    const int co0    = cohalf * 64 + wv * 16;
    const int lanelo = lane & 15;
    const int kgi    = (lane >> 4) * 8;                 // ci sub-offset (elems)
    const unsigned kg2 = (unsigned)(lane >> 4) * 16;    // ci sub-offset (bytes)

    // ---- weights -> registers (once per block; 72 VGPRs, static-indexed) ----
    half8 wH[9][2];
    {
        const int co = co0 + lanelo;
        const _Float16* wh = whi + (size_t)co * CIc + kgi;
        #pragma unroll
        for (int t = 0; t < 9; ++t)
            #pragma unroll
            for (int cs = 0; cs < 2; ++cs)
                wH[t][cs] = *(const half8*)(wh + (size_t)t * COc * CIc + cs * 32);
    }

    // ---- staging split: issue (global->xr regs) / write (xr->LDS) ----
    float xr[3][8];   // in-flight x row; short live range (across barrier only)

    auto issueRow = [&](int rabs) {
        #pragma unroll
        for (int c = 0; c < 3; ++c) {
            const int it = tid + c * 256;
            if (it < 528) {
                const int px1 = it % 66, cig = it / 66;
                const int px = px1 - 1;
                const bool val = ((unsigned)px < 64u) && ((unsigned)rabs < 64u);
                const float* xp = x + (((size_t)n * CIc + cig * 8) * HHc
                                       + (val ? rabs : 0)) * WWc + (val ? px : 0);
                #pragma unroll
                for (int j2 = 0; j2 < 8; ++j2)
                    xr[c][j2] = val ? xp[j2 * (HHc * WWc)] : 0.0f;
            }
        }
    };
    auto writeRow = [&](int rabs) {
        const int slot = (rabs + 8) & 3;
        char* sb = xsb + slot * 8448;
        #pragma unroll
        for (int c = 0; c < 3; ++c) {
            const int it = tid + c * 256;
            if (it < 528) {
                const int px1 = it % 66, cig = it / 66;
                half8 hv;
                #pragma unroll
                for (int j2 = 0; j2 < 8; ++j2)
                    hv[j2] = (_Float16)xr[c][j2];
                const unsigned off = (unsigned)px1 * 128
                                   + (((unsigned)cig * 16) ^ (((unsigned)px1 & 7) << 4));
                *(half8*)(sb + off) = hv;
            }
        }
    };

    // ---- prologue: rows y0-1..y0+1 staged; y0+2 left in flight in xr ----
    issueRow(y0 - 1); writeRow(y0 - 1);
    issueRow(y0);     writeRow(y0);
    issueRow(y0 + 1); writeRow(y0 + 1);
    issueRow(y0 + 2);
    asm volatile("s_waitcnt lgkmcnt(0)" ::: "memory");
    __builtin_amdgcn_s_barrier();

    const float beta = beta_p[0];
    const float omb  = 1.0f - beta;
    float rnv[4], biv[4];
    #pragma unroll
    for (int r = 0; r < 4; ++r) {
        const int co = co0 + (lane >> 4) * 4 + r;
        rnv[r] = rnormf[co];
        biv[r] = bias[co];
    }

    for (int j = 0; j < 4; ++j) {
        const int y = y0 + j;

        // write staged row y+2 (xr loads issued last row -> long landed)
        if (j < 3) writeRow(y + 2);

        // ---- MFMA main loop: 72 ds_read_b128 + 72 MFMA, single product ----
        f32x4 acc[4];
        #pragma unroll
        for (int pf = 0; pf < 4; ++pf) acc[pf] = f32x4{0.f, 0.f, 0.f, 0.f};

        __builtin_amdgcn_s_setprio(1);
        #pragma unroll
        for (int t = 0; t < 9; ++t) {
            const int dy = t / 3, dx = t % 3;
            const unsigned sbase = (unsigned)((y - 1 + dy + 8) & 3) * 8448;
            #pragma unroll
            for (int cs = 0; cs < 2; ++cs) {
                #pragma unroll
                for (int pf = 0; pf < 4; ++pf) {
                    const int px1 = pf * 16 + lanelo + dx;
                    const unsigned ob = sbase + (unsigned)px1 * 128
                        + (((unsigned)(cs * 64) + kg2) ^ (((unsigned)px1 & 7) << 4));
                    const half8 bh = *(const half8*)(xsb + ob);
                    acc[pf] = __builtin_amdgcn_mfma_f32_16x16x32_f16(wH[t][cs], bh, acc[pf], 0, 0, 0);
                }
            }
        }
        __builtin_amdgcn_s_setprio(0);

        // ---- epilogue: LIF + spike + flag mask (1-ballot fast path) ----
        unsigned flm = 0u;
        #pragma unroll
        for (int pf = 0; pf < 4; ++pf) {
            const int px = pf * 16 + lanelo;
            #pragma unroll
            for (int r = 0; r < 4; ++r) {
                const int co = co0 + (lane >> 4) * 4 + r;
                const size_t idx = (((size_t)n * COc + co) * HHc + y) * WWc + px;
                const float nm   = fmaf(mem[idx], beta, acc[pf][r] * omb);
                const float mthr = fmaf(nm, rnv[r], -biv[r]);
                // s = (mthr>0)+(mthr>1)+(mthr>2)+(mthr>3) == clamp(ceil,0,4)
                const float cm = fminf(fmaxf(ceilf(mthr), 0.0f), 4.0f);
                out_spk[idx] = cm;
                out_mem[idx] = (cm > 0.0f) ? 0.0f : nm;
                const float fr = rintf(mthr);
                const bool fl = (fabsf(mthr - fr) < EPSB) &
                                (fr >= 0.0f) & (fr <= 3.5f);
                flm |= ((unsigned)fl) << (pf * 4 + r);
            }
        }
        if (__ballot(flm != 0u)) {          // rare fast path
            #pragma unroll
            for (int pf = 0; pf < 4; ++pf) {
                #pragma unroll
                for (int r = 0; r < 4; ++r) {
                    const unsigned long long msk =
                        __ballot((flm >> (pf * 4 + r)) & 1u);
                    if (msk) {
                        unsigned wb = 0;
                        if (lane == 0)
                            wb = atomicAdd(counter, (unsigned)__popcll(msk));
                        wb = __shfl(wb, 0);
                        if ((flm >> (pf * 4 + r)) & 1u) {
                            const int px = pf * 16 + lanelo;
                            const int co = co0 + (lane >> 4) * 4 + r;
                            const size_t idx =
                                (((size_t)n * COc + co) * HHc + y) * WWc + px;
                            const unsigned pos = wb +
                                (unsigned)__popcll(msk & ((1ull << lane) - 1ull));
                            if (pos < CAPc) list[pos] = (unsigned)idx;
                        }
                    }
                }
            }
        }

        // refill xr for row y+3 AFTER epilogue (short live range; the loads
        // cross the raw barrier and land during next row's start)
        if (j < 2) issueRow(y + 3);

        // row boundary: LDS writes/reads retire; vmem stays in flight.
        asm volatile("s_waitcnt lgkmcnt(0)" ::: "memory");
        __builtin_amdgcn_s_barrier();
    }
}

// ---- Pass B: exact fp64 recompute of flagged pixels (wave per pixel, lane=ci) ----
__global__ __launch_bounds__(256) void fixB(
    const float* __restrict__ x, const float* __restrict__ mem,
    const float* __restrict__ beta_p, const float* __restrict__ bias,
    const double* __restrict__ normd, const double* __restrict__ wdT,
    const unsigned* __restrict__ counter, const unsigned* __restrict__ list,
    float* __restrict__ out_spk, float* __restrict__ out_mem)
{
    const int lane  = threadIdx.x & 63;
    const int wave  = blockIdx.x * 4 + (threadIdx.x >> 6);
    const int nwave = gridDim.x * 4;
    const unsigned cnt = min(counter[0], CAPc);
    const double beta = (double)beta_p[0];
    const double omb  = 1.0 - beta;

    for (unsigned p = wave; p < cnt; p += nwave) {
        const unsigned idx = list[p];
        const int xp = idx & 63, yp = (idx >> 6) & 63;
        const int co = (idx >> 12) & 127, n = idx >> 19;

        const float*  xc = x + ((size_t)n * CIc + lane) * (HHc * WWc);
        const double* wt = wdT + (size_t)co * 9 * CIc + lane;

        double a = 0.0;
        #pragma unroll
        for (int t = 0; t < 9; ++t) {
            const int yy = yp + t / 3 - 1, xx = xp + t % 3 - 1;
            const bool v = ((unsigned)yy < 64u) && ((unsigned)xx < 64u);
            const int yyc = min(max(yy, 0), 63), xxc = min(max(xx, 0), 63);
            const double xv = v ? (double)xc[yyc * WWc + xxc] : 0.0;
            a = fma(xv, wt[t * CIc], a);
        }
        #pragma unroll
        for (int off = 32; off; off >>= 1) a += __shfl_xor(a, off);

        if (lane == 0) {
            const double nm   = (double)mem[idx] * beta + a * omb;
            const double mthr = nm / normd[co] - (double)bias[co];
            const int s = (mthr > 0.) + (mthr > 1.) + (mthr > 2.) + (mthr > 3.);
            out_spk[idx] = (float)s;
            out_mem[idx] = (s > 0) ? 0.0f : (float)nm;
        }
    }
}

// ---- Fallback (ws too small): all-fp64 direct conv ----
__global__ __launch_bounds__(256) void conv_fp64_fb(
    const float* __restrict__ x, const float* __restrict__ mem,
    const float* __restrict__ w, const float* __restrict__ beta_p,
    const float* __restrict__ bias, const double* __restrict__ normd,
    float* __restrict__ out_spk, float* __restrict__ out_mem)
{
    const int ix = threadIdx.x, iy = blockIdx.x * 4 + threadIdx.y;
    const int co0 = blockIdx.y * 8, n = blockIdx.z;
    bool valid[9]; int xoff[9];
    #pragma unroll
    for (int kh = 0; kh < 3; ++kh) {
        const int yy = iy + kh - 1;
        #pragma unroll
        for (int kw = 0; kw < 3; ++kw) {
            const int xx = ix + kw - 1, t = kh * 3 + kw;
            valid[t] = ((unsigned)yy < 64u) && ((unsigned)xx < 64u);
            xoff[t]  = yy * WWc + xx;
        }
    }
    double acc[8];
    #pragma unroll
    for (int j = 0; j < 8; ++j) acc[j] = 0.0;
    const float* xb = x + (size_t)n * CIc * HHc * WWc;
    for (int ci = 0; ci < CIc; ++ci) {
        const float* xc = xb + (size_t)ci * HHc * WWc;
        #pragma unroll
        for (int t = 0; t < 9; ++t) {
            const double xv = valid[t] ? (double)xc[xoff[t]] : 0.0;
            const float* wt = w + ((size_t)t * CIc + ci) * COc + co0;
            #pragma unroll
            for (int j = 0; j < 8; ++j) acc[j] = fma(xv, (double)wt[j], acc[j]);
        }
    }
    const double beta = (double)beta_p[0], omb = 1.0 - beta;
    const size_t base = (((size_t)n * COc + co0) * HHc + iy) * WWc + ix;
    #pragma unroll
    for (int j = 0; j < 8; ++j) {
        const size_t idx = base + (size_t)j * (HHc * WWc);
        const double nm   = (double)mem[idx] * beta + acc[j] * omb;
        const double mthr = nm / normd[co0 + j] - (double)bias[co0 + j];
        const int s = (mthr > 0.) + (mthr > 1.) + (mthr > 2.) + (mthr > 3.);
        out_spk[idx] = (float)s;
        out_mem[idx] = (s > 0) ? 0.0f : (float)nm;
    }
}

extern "C" void kernel_launch(void* const* d_in, const int* in_sizes, int n_in,
                              void* d_out, int out_size, void* d_ws, size_t ws_size,
                              hipStream_t stream) {
    const float* x      = (const float*)d_in[0];
    const float* mem    = (const float*)d_in[1];
    const float* w      = (const float*)d_in[2];
    const float* beta_p = (const float*)d_in[3];
    const float* bias   = (const float*)d_in[4];

    float* out_spk = (float*)d_out;
    float* out_mem = out_spk + (size_t)NBc * COc * HHc * WWc;

    char* ws = (char*)d_ws;
    unsigned* counter = (unsigned*)(ws + O_CNT);
    double*   normd   = (double*)(ws + O_NORMD);
    float*    rnormf  = (float*)(ws + O_RNORM);
    double*   wdT     = (double*)(ws + O_WDT);
    _Float16* whi     = (_Float16*)(ws + O_WHI);
    unsigned* list    = (unsigned*)(ws + O_LIST);

    if (ws_size >= WS_NEED) {
        prep_kernel<<<128 + 288, 256, 0, stream>>>(w, normd, rnormf, wdT, whi,
                                                   counter);
        dim3 grdM(16, 2, NBc);             // 16 y-stripes x 2 co-halves x 32 n
        convM<<<grdM, 256, 0, stream>>>(x, mem, whi, beta_p, bias, rnormf,
                                        out_spk, out_mem, counter, list);
        fixB<<<512, 256, 0, stream>>>(x, mem, beta_p, bias, normd, wdT,
                                      counter, list, out_spk, out_mem);
    } else {
        prep_kernel<<<128, 256, 0, stream>>>(w, normd, rnormf, wdT, nullptr,
                                             counter);
        dim3 blk(WWc, 4, 1);
        dim3 grd(HHc / 4, COc / 8, NBc);
        conv_fp64_fb<<<grd, blk, 0, stream>>>(x, mem, w, beta_p, bias, normd,
                                              out_spk, out_mem);
    }
}

// Round 7
// 440.936 us; speedup vs baseline: 1.1874x; 1.1874x over previous
//
#include <hip/hip_runtime.h>

// SparseSpikingConv2D — Round 13: R12 single-product core, honest registers.
// R12 post-mortem: __launch_bounds__(256,4) made the compiler split the
// unified file (arch VGPR=64) -> spill storm (FETCH 292 / WRITE 374 MB),
// convM 314 us. Third confirmation: VGPR cap < ~130 => spill storm; only
// (256,2) ever compiled clean (R10/R11: 124-128, no/low spill).
// R13: keep R12's validated single-product fp16 (PASSED, MFMA /3, LDS /2,
// ring 33.8 KB, EPSB 2e-4), revert to (256,2), drop xr[3][8] (24 regs) ->
// direct load->convert->write staging (short-lived temps). True demand ~120:
// if alloc <=128, LDS admits 4 blocks/CU = 16 waves -> TLP covers the stage
// latency instead of registers. Everything else byte-identical to R12.

typedef _Float16 half8 __attribute__((ext_vector_type(8)));
typedef float f32x4 __attribute__((ext_vector_type(4)));

constexpr int CIc = 64, COc = 128, HHc = 64, WWc = 64, NBc = 32;
constexpr float EPSB = 2e-4f;        // borderline band on mthr
constexpr unsigned CAPc = 1u << 18;  // fixup list capacity

// workspace layout (bytes)
constexpr size_t O_CNT   = 0;                    // 1 uint (padded 16)
constexpr size_t O_NORMD = 16;                   // 128 double
constexpr size_t O_RNORM = O_NORMD + 1024;       // 128 float
constexpr size_t O_WDT   = O_RNORM + 512;        // [co][t][ci] double = 589824 B
constexpr size_t O_WHI   = O_WDT + 589824;       // [t][co][ci] fp16 = 147456 B
constexpr size_t O_LIST  = O_WHI + 147456;       // CAPc uint
constexpr size_t WS_NEED = O_LIST + (size_t)CAPc * 4;   // ~1.8 MB

// Fused prep: blocks 0..127 -> norm (co=bx, 64-lane fp64 butterfly);
// blocks 128..415 -> wdT (fp64, for fixB) + whi (fp16, for convM).
__global__ void prep_kernel(const float* __restrict__ w, double* __restrict__ normd,
                            float* __restrict__ rnormf, double* __restrict__ wdT,
                            _Float16* __restrict__ whi, unsigned* __restrict__ counter) {
    const int bx = blockIdx.x;
    if (bx < 128) {
        const int co = bx, lane = threadIdx.x & 63;
        if (threadIdx.x >= 64) return;
        double s = 0.0;
        #pragma unroll
        for (int k = 0; k < 9; ++k) {
            const double v = (double)w[(k * 64 + lane) * COc + co];
            s = fma(v, v, s);
        }
        #pragma unroll
        for (int off = 32; off; off >>= 1) s += __shfl_xor(s, off);
        if (lane == 0) {
            s += 1e-8;
            normd[co]  = s;
            rnormf[co] = (float)(1.0 / s);
            if (co == 0) counter[0] = 0u;
        }
    } else {
        const int i = (bx - 128) * 256 + threadIdx.x;  // over 73728
        if (i >= 9 * CIc * COc) return;
        const int ci = i & 63, t = (i >> 6) % 9, co = i / (9 * 64);
        const float v = w[(t * CIc + ci) * COc + co];
        wdT[i] = (double)v;                            // wdT[co][t][ci]
        if (whi) {
            const int i2 = (t * COc + co) * CIc + ci;  // [t][co][ci]
            whi[i2] = (_Float16)v;
        }
    }
}

// ---- Pass A (MFMA, single-product fp16): 64co x 64px x 4 streamed rows ----
// Block = 256 thr = 4 waves; wave wv owns couts [co0, co0+16), co0 =
// cohalf*64 + wv*16; weights in 72 VGPRs (wH[9][2], loaded once).
// 4-slot LDS row ring (8448 B/slot, 33792 B total -> 4 blocks/CU if
// VGPR <= 128). Grid (16,2,32) = 1024 blocks = 4/CU exactly.
// Per row j: stage(y+2) [direct load->cvt->ds_write] -> MFMA (72 ds_read +
// 72 MFMA) -> epilogue -> lgkmcnt(0) + raw s_barrier (vmem in flight).
// Swizzle byte^=(px1&7)<<4 on write AND read. D: row=co=(lane>>4)*4+r,
// col=px=lane&15 (m89 layout). MFMA order identical to R12.
__global__ __launch_bounds__(256, 2) void convM(
    const float* __restrict__ x,       // [32,64,64,64]
    const float* __restrict__ mem,     // [32,128,64,64]
    const _Float16* __restrict__ whi,  // [9,128,64]
    const float* __restrict__ beta_p,
    const float* __restrict__ bias,
    const float* __restrict__ rnormf,
    float* __restrict__ out_spk, float* __restrict__ out_mem,
    unsigned* __restrict__ counter, unsigned* __restrict__ list)
{
    // 4 slots x 8448 B (66 px1 x 64 ci fp16, swizzled) = 33792 B.
    __shared__ half8 xs[2112];
    char* xsb = (char*)(&xs[0]);

    const int tid = threadIdx.x;
    const int y0 = blockIdx.x * 4;
    const int cohalf = blockIdx.y;
    const int n = blockIdx.z;

    const int lane   = tid & 63;
    const int wv     = tid >> 6;
    const int co0    = cohalf * 64 + wv * 16;
    const int lanelo = lane & 15;
    const int kgi    = (lane >> 4) * 8;                 // ci sub-offset (elems)
    const unsigned kg2 = (unsigned)(lane >> 4) * 16;    // ci sub-offset (bytes)

    // ---- weights -> registers (once per block; 72 VGPRs, static-indexed) ----
    half8 wH[9][2];
    {
        const int co = co0 + lanelo;
        const _Float16* wh = whi + (size_t)co * CIc + kgi;
        #pragma unroll
        for (int t = 0; t < 9; ++t)
            #pragma unroll
            for (int cs = 0; cs < 2; ++cs)
                wH[t][cs] = *(const half8*)(wh + (size_t)t * COc * CIc + cs * 32);
    }

    // ---- direct staging: load -> convert -> ds_write, short-lived temps ----
    auto stageRow = [&](int rabs) {
        const int slot = (rabs + 8) & 3;
        char* sb = xsb + slot * 8448;
        #pragma unroll
        for (int c = 0; c < 3; ++c) {
            const int it = tid + c * 256;
            if (it < 528) {
                const int px1 = it % 66, cig = it / 66;
                const int px = px1 - 1;
                const bool val = ((unsigned)px < 64u) && ((unsigned)rabs < 64u);
                const float* xp = x + (((size_t)n * CIc + cig * 8) * HHc
                                       + (val ? rabs : 0)) * WWc + (val ? px : 0);
                half8 hv;
                #pragma unroll
                for (int j2 = 0; j2 < 8; ++j2)
                    hv[j2] = (_Float16)(val ? xp[j2 * (HHc * WWc)] : 0.0f);
                const unsigned off = (unsigned)px1 * 128
                                   + (((unsigned)cig * 16) ^ (((unsigned)px1 & 7) << 4));
                *(half8*)(sb + off) = hv;
            }
        }
    };

    // ---- prologue: rows y0-1..y0+1 -> slots ----
    stageRow(y0 - 1);
    stageRow(y0);
    stageRow(y0 + 1);
    asm volatile("s_waitcnt lgkmcnt(0)" ::: "memory");
    __builtin_amdgcn_s_barrier();

    const float beta = beta_p[0];
    const float omb  = 1.0f - beta;
    float rnv[4], biv[4];
    #pragma unroll
    for (int r = 0; r < 4; ++r) {
        const int co = co0 + (lane >> 4) * 4 + r;
        rnv[r] = rnormf[co];
        biv[r] = bias[co];
    }

    for (int j = 0; j < 4; ++j) {
        const int y = y0 + j;

        // stage row y+2 into slot (y+2)&3 (disjoint from this row's reads;
        // its last reader was row j-1, separated by the barrier). Stage
        // stalls overlap other resident blocks' MFMA (4 blocks/CU).
        if (j < 3) stageRow(y + 2);

        // ---- MFMA main loop: 72 ds_read_b128 + 72 MFMA, single product ----
        f32x4 acc[4];
        #pragma unroll
        for (int pf = 0; pf < 4; ++pf) acc[pf] = f32x4{0.f, 0.f, 0.f, 0.f};

        __builtin_amdgcn_s_setprio(1);
        #pragma unroll
        for (int t = 0; t < 9; ++t) {
            const int dy = t / 3, dx = t % 3;
            const unsigned sbase = (unsigned)((y - 1 + dy + 8) & 3) * 8448;
            #pragma unroll
            for (int cs = 0; cs < 2; ++cs) {
                #pragma unroll
                for (int pf = 0; pf < 4; ++pf) {
                    const int px1 = pf * 16 + lanelo + dx;
                    const unsigned ob = sbase + (unsigned)px1 * 128
                        + (((unsigned)(cs * 64) + kg2) ^ (((unsigned)px1 & 7) << 4));
                    const half8 bh = *(const half8*)(xsb + ob);
                    acc[pf] = __builtin_amdgcn_mfma_f32_16x16x32_f16(wH[t][cs], bh, acc[pf], 0, 0, 0);
                }
            }
        }
        __builtin_amdgcn_s_setprio(0);

        // ---- epilogue: LIF + spike + flag mask (1-ballot fast path) ----
        unsigned flm = 0u;
        #pragma unroll
        for (int pf = 0; pf < 4; ++pf) {
            const int px = pf * 16 + lanelo;
            #pragma unroll
            for (int r = 0; r < 4; ++r) {
                const int co = co0 + (lane >> 4) * 4 + r;
                const size_t idx = (((size_t)n * COc + co) * HHc + y) * WWc + px;
                const float nm   = fmaf(mem[idx], beta, acc[pf][r] * omb);
                const float mthr = fmaf(nm, rnv[r], -biv[r]);
                // s = (mthr>0)+(mthr>1)+(mthr>2)+(mthr>3) == clamp(ceil,0,4)
                const float cm = fminf(fmaxf(ceilf(mthr), 0.0f), 4.0f);
                out_spk[idx] = cm;
                out_mem[idx] = (cm > 0.0f) ? 0.0f : nm;
                const float fr = rintf(mthr);
                const bool fl = (fabsf(mthr - fr) < EPSB) &
                                (fr >= 0.0f) & (fr <= 3.5f);
                flm |= ((unsigned)fl) << (pf * 4 + r);
            }
        }
        if (__ballot(flm != 0u)) {          // rare fast path
            #pragma unroll
            for (int pf = 0; pf < 4; ++pf) {
                #pragma unroll
                for (int r = 0; r < 4; ++r) {
                    const unsigned long long msk =
                        __ballot((flm >> (pf * 4 + r)) & 1u);
                    if (msk) {
                        unsigned wb = 0;
                        if (lane == 0)
                            wb = atomicAdd(counter, (unsigned)__popcll(msk));
                        wb = __shfl(wb, 0);
                        if ((flm >> (pf * 4 + r)) & 1u) {
                            const int px = pf * 16 + lanelo;
                            const int co = co0 + (lane >> 4) * 4 + r;
                            const size_t idx =
                                (((size_t)n * COc + co) * HHc + y) * WWc + px;
                            const unsigned pos = wb +
                                (unsigned)__popcll(msk & ((1ull << lane) - 1ull));
                            if (pos < CAPc) list[pos] = (unsigned)idx;
                        }
                    }
                }
            }
        }

        // row boundary: LDS writes/reads retire; vmem stays in flight.
        asm volatile("s_waitcnt lgkmcnt(0)" ::: "memory");
        __builtin_amdgcn_s_barrier();
    }
}

// ---- Pass B: exact fp64 recompute of flagged pixels (wave per pixel, lane=ci) ----
__global__ __launch_bounds__(256) void fixB(
    const float* __restrict__ x, const float* __restrict__ mem,
    const float* __restrict__ beta_p, const float* __restrict__ bias,
    const double* __restrict__ normd, const double* __restrict__ wdT,
    const unsigned* __restrict__ counter, const unsigned* __restrict__ list,
    float* __restrict__ out_spk, float* __restrict__ out_mem)
{
    const int lane  = threadIdx.x & 63;
    const int wave  = blockIdx.x * 4 + (threadIdx.x >> 6);
    const int nwave = gridDim.x * 4;
    const unsigned cnt = min(counter[0], CAPc);
    const double beta = (double)beta_p[0];
    const double omb  = 1.0 - beta;

    for (unsigned p = wave; p < cnt; p += nwave) {
        const unsigned idx = list[p];
        const int xp = idx & 63, yp = (idx >> 6) & 63;
        const int co = (idx >> 12) & 127, n = idx >> 19;

        const float*  xc = x + ((size_t)n * CIc + lane) * (HHc * WWc);
        const double* wt = wdT + (size_t)co * 9 * CIc + lane;

        double a = 0.0;
        #pragma unroll
        for (int t = 0; t < 9; ++t) {
            const int yy = yp + t / 3 - 1, xx = xp + t % 3 - 1;
            const bool v = ((unsigned)yy < 64u) && ((unsigned)xx < 64u);
            const int yyc = min(max(yy, 0), 63), xxc = min(max(xx, 0), 63);
            const double xv = v ? (double)xc[yyc * WWc + xxc] : 0.0;
            a = fma(xv, wt[t * CIc], a);
        }
        #pragma unroll
        for (int off = 32; off; off >>= 1) a += __shfl_xor(a, off);

        if (lane == 0) {
            const double nm   = (double)mem[idx] * beta + a * omb;
            const double mthr = nm / normd[co] - (double)bias[co];
            const int s = (mthr > 0.) + (mthr > 1.) + (mthr > 2.) + (mthr > 3.);
            out_spk[idx] = (float)s;
            out_mem[idx] = (s > 0) ? 0.0f : (float)nm;
        }
    }
}

// ---- Fallback (ws too small): all-fp64 direct conv ----
__global__ __launch_bounds__(256) void conv_fp64_fb(
    const float* __restrict__ x, const float* __restrict__ mem,
    const float* __restrict__ w, const float* __restrict__ beta_p,
    const float* __restrict__ bias, const double* __restrict__ normd,
    float* __restrict__ out_spk, float* __restrict__ out_mem)
{
    const int ix = threadIdx.x, iy = blockIdx.x * 4 + threadIdx.y;
    const int co0 = blockIdx.y * 8, n = blockIdx.z;
    bool valid[9]; int xoff[9];
    #pragma unroll
    for (int kh = 0; kh < 3; ++kh) {
        const int yy = iy + kh - 1;
        #pragma unroll
        for (int kw = 0; kw < 3; ++kw) {
            const int xx = ix + kw - 1, t = kh * 3 + kw;
            valid[t] = ((unsigned)yy < 64u) && ((unsigned)xx < 64u);
            xoff[t]  = yy * WWc + xx;
        }
    }
    double acc[8];
    #pragma unroll
    for (int j = 0; j < 8; ++j) acc[j] = 0.0;
    const float* xb = x + (size_t)n * CIc * HHc * WWc;
    for (int ci = 0; ci < CIc; ++ci) {
        const float* xc = xb + (size_t)ci * HHc * WWc;
        #pragma unroll
        for (int t = 0; t < 9; ++t) {
            const double xv = valid[t] ? (double)xc[xoff[t]] : 0.0;
            const float* wt = w + ((size_t)t * CIc + ci) * COc + co0;
            #pragma unroll
            for (int j = 0; j < 8; ++j) acc[j] = fma(xv, (double)wt[j], acc[j]);
        }
    }
    const double beta = (double)beta_p[0], omb = 1.0 - beta;
    const size_t base = (((size_t)n * COc + co0) * HHc + iy) * WWc + ix;
    #pragma unroll
    for (int j = 0; j < 8; ++j) {
        const size_t idx = base + (size_t)j * (HHc * WWc);
        const double nm   = (double)mem[idx] * beta + acc[j] * omb;
        const double mthr = nm / normd[co0 + j] - (double)bias[co0 + j];
        const int s = (mthr > 0.) + (mthr > 1.) + (mthr > 2.) + (mthr > 3.);
        out_spk[idx] = (float)s;
        out_mem[idx] = (s > 0) ? 0.0f : (float)nm;
    }
}

extern "C" void kernel_launch(void* const* d_in, const int* in_sizes, int n_in,
                              void* d_out, int out_size, void* d_ws, size_t ws_size,
                              hipStream_t stream) {
    const float* x      = (const float*)d_in[0];
    const float* mem    = (const float*)d_in[1];
    const float* w      = (const float*)d_in[2];
    const float* beta_p = (const float*)d_in[3];
    const float* bias   = (const float*)d_in[4];

    float* out_spk = (float*)d_out;
    float* out_mem = out_spk + (size_t)NBc * COc * HHc * WWc;

    char* ws = (char*)d_ws;
    unsigned* counter = (unsigned*)(ws + O_CNT);
    double*   normd   = (double*)(ws + O_NORMD);
    float*    rnormf  = (float*)(ws + O_RNORM);
    double*   wdT     = (double*)(ws + O_WDT);
    _Float16* whi     = (_Float16*)(ws + O_WHI);
    unsigned* list    = (unsigned*)(ws + O_LIST);

    if (ws_size >= WS_NEED) {
        prep_kernel<<<128 + 288, 256, 0, stream>>>(w, normd, rnormf, wdT, whi,
                                                   counter);
        dim3 grdM(16, 2, NBc);             // 16 y-stripes x 2 co-halves x 32 n
        convM<<<grdM, 256, 0, stream>>>(x, mem, whi, beta_p, bias, rnormf,
                                        out_spk, out_mem, counter, list);
        fixB<<<512, 256, 0, stream>>>(x, mem, beta_p, bias, normd, wdT,
                                      counter, list, out_spk, out_mem);
    } else {
        prep_kernel<<<128, 256, 0, stream>>>(w, normd, rnormf, wdT, nullptr,
                                             counter);
        dim3 blk(WWc, 4, 1);
        dim3 grd(HHc / 4, COc / 8, NBc);
        conv_fp64_fb<<<grd, blk, 0, stream>>>(x, mem, w, beta_p, bias, normd,
                                              out_spk, out_mem);
    }
}